// Round 6
// baseline (207.071 us; speedup 1.0000x reference)
//
#include <hip/hip_runtime.h>

#pragma clang fp contract(off)

// Problem constants (fixed by setup_inputs): B=32, G=50, H=W=64, A=9.
#define BB 32
#define GG 50
#define AA 9
#define HH 64
#define WW 64
#define KAT (HH*WW*AA)          // 36864 total anchors
#define NANC 18624              // inside-anchor count (compile-time exact)
#define NCAP 20480              // stride for per-image per-anchor arrays
#define MAXC 4096               // candidate list cap per image
#define NUMFG 128               // int(0.5 * 256)
#define RPNB 256
#define BG_T 0.05f              // bg priority pre-filter (256th smallest ~0.0143)
#define LAB_SZ (BB*AA*HH*WW)    // 1179648
#define NGTB (BB*GG)            // 1600 gtmax-role blocks
#define NPREPB (KAT/256)        // 144 prep-role blocks

// Anchor (w,h) per type, order = ratios{0.5,1,2} x scales{8,16,32}
__constant__ float c_aw[9] = {184.f,368.f,736.f,128.f,256.f,512.f, 88.f,176.f,352.f};
__constant__ float c_ah[9] = { 96.f,192.f,384.f,128.f,256.f,512.f,176.f,352.f,704.f};
__constant__ int   c_awi[9] = {184,368,736,128,256,512, 88,176,352};
__constant__ int   c_ahi[9] = { 96,192,384,128,256,512,176,352,704};
// Inside-region integer ranges per type (derived from the exact fp32 inside
// test: x in [(w-1+16)>>5, (2032-(w-1))>>5], same for y) — compile-time.
__constant__ int c_xlo[9] = {6,11,23,4,8,16,3,5,11};
__constant__ int c_xhi[9] = {57,52,40,59,55,47,60,58,52};
__constant__ int c_nx [9] = {52,42,18,56,48,32,58,54,42};
__constant__ int c_ylo[9] = {3,6,12,4,8,16,5,11,22};
__constant__ int c_yhi[9] = {60,57,51,59,55,47,58,52,41};
// a-major base offsets (prefix over nx*ny): sums to 18624
__constant__ int c_base[9] = {0,3016,5200,5920,9056,11360,12384,15516,17784};

__device__ __forceinline__ unsigned rotl32(unsigned v, int d) {
  return (v << d) | (v >> (32 - d));
}

// Threefry-2x32, 20 rounds — matches jax._src.prng.threefry2x32
__device__ __forceinline__ void tf2x32(unsigned k0, unsigned k1,
                                       unsigned x0, unsigned x1,
                                       unsigned &o0, unsigned &o1) {
  unsigned ks2 = k0 ^ k1 ^ 0x1BD11BDAu;
  x0 += k0; x1 += k1;
#define TF_R(r) { x0 += x1; x1 = rotl32(x1, (r)); x1 ^= x0; }
  TF_R(13) TF_R(15) TF_R(26) TF_R(6)
  x0 += k1;  x1 += ks2 + 1u;
  TF_R(17) TF_R(29) TF_R(16) TF_R(24)
  x0 += ks2; x1 += k0 + 2u;
  TF_R(13) TF_R(15) TF_R(26) TF_R(6)
  x0 += k0;  x1 += k1 + 3u;
  TF_R(17) TF_R(29) TF_R(16) TF_R(24)
  x0 += k1;  x1 += ks2 + 4u;
  TF_R(13) TF_R(15) TF_R(26) TF_R(6)
  x0 += ks2; x1 += k0 + 5u;
#undef TF_R
  o0 = x0; o1 = x1;
}

__device__ __forceinline__ float bits_to_uniform(unsigned bits) {
  return __uint_as_float((bits >> 9) | 0x3f800000u) - 1.0f;
}

// uniform(key,(N,)) word i — jax_threefry_partitionable=True path (verified R1)
__device__ __forceinline__ float pri_uniform(unsigned k0, unsigned k1, int i) {
  unsigned o0, o1;
  tf2x32(k0, k1, 0u, (unsigned)i, o0, o1);
  return bits_to_uniform(o0 ^ o1);
}

__device__ __forceinline__ void box_from_ayx(int a, int x, int y,
                                             float &ax1, float &ay1, float &ax2, float &ay2) {
  float hw = 0.5f * (c_aw[a] - 1.0f);
  float hh = 0.5f * (c_ah[a] - 1.0f);
  float cx = (float)(16 * x) + 7.5f;
  float cy = (float)(16 * y) + 7.5f;
  ax1 = cx - hw; ay1 = cy - hh; ax2 = cx + hw; ay2 = cy + hh;
}

// ---- K1: fused prep (a-major tables + keys) + pruned gt_max -------------
__global__ void __launch_bounds__(256) k_pg(
    const float* __restrict__ gt,
    float4* __restrict__ abox, float* __restrict__ aar, int* __restrict__ iref,
    unsigned* __restrict__ keyf, unsigned* __restrict__ keyb,
    int* __restrict__ fg_cnt, int* __restrict__ bg_cnt,
    float* __restrict__ gt_max) {
  if (blockIdx.x >= NGTB) {
    // ---- prep role: one thread per ka ----
    int tid = (blockIdx.x - NGTB) * 256 + threadIdx.x;
    if (tid < BB) {
      int b = tid;
      fg_cnt[b] = 0; bg_cnt[b] = 0;
      unsigned h, l, f0, f1, g0, g1;
      tf2x32(0u, 42u, 0u, (unsigned)b, h, l);      // split(key(42),32)[b]
      tf2x32(h, l, 0u, 0u, f0, f1);                // kf
      tf2x32(h, l, 0u, 1u, g0, g1);                // kb
      keyf[2*b] = f0; keyf[2*b+1] = f1;
      keyb[2*b] = g0; keyb[2*b+1] = g1;
    }
    int ka = tid;
    int a = ka % AA, pos = ka / AA, x = pos & 63, y = pos >> 6;
    int pre = 0; bool mine = false;
#pragma unroll
    for (int t = 0; t < 9; ++t) {                  // iref = inside-order prefix
      int hw2 = c_awi[t] - 1, hh2 = c_ahi[t] - 1;
      int xlo = (hw2 + 16) >> 5, xhi = (2032 - hw2) >> 5;
      int ylo = (hh2 + 16) >> 5, yhi = (2032 - hh2) >> 5;
      int nx = xhi - xlo + 1;
      int rb = min(y, yhi + 1) - ylo; rb = max(rb, 0);
      pre += nx * rb;
      bool iny = (y >= ylo) && (y <= yhi);
      if (iny) {
        int cb = min(x, xhi + 1) - xlo; cb = max(cb, 0);
        pre += cb;
        bool ins = (x >= xlo) && (x <= xhi);
        if (ins && t < a) pre++;
        if (t == a) mine = ins;
      }
    }
    if (mine) {
      int j = c_base[a] + (y - c_ylo[a]) * c_nx[a] + (x - c_xlo[a]);  // a-major
      float ax1, ay1, ax2, ay2;
      box_from_ayx(a, x, y, ax1, ay1, ax2, ay2);
      abox[j] = make_float4(ax1, ay1, ax2, ay2);
      aar[j] = ((ax2 - ax1) + 1.0f) * ((ay2 - ay1) + 1.0f);
      iref[j] = pre;
    }
    return;
  }
  // ---- gtmax role: one block per (b,g), pruned to the overlap window ----
  int b = blockIdx.x / GG, g = blockIdx.x % GG;
  const float* gr = gt + (b * GG + g) * 4;
  float gx1 = gr[0], gy1 = gr[1], gx2 = gr[2], gy2 = gr[3];
  float gar = ((gx2 - gx1) + 1.0f) * ((gy2 - gy1) + 1.0f);
  int lane = threadIdx.x & 63, wv = threadIdx.x >> 6;
  float best = 0.0f;                               // IoU >= 0; matches ref max
#pragma unroll
  for (int t = 0; t < 9; ++t) {
    float hw = 0.5f * (c_aw[t] - 1.0f), hh = 0.5f * (c_ah[t] - 1.0f);
    // conservative (+-1 cell) overlap window; excluded anchors have ov == 0
    int x0 = max(c_xlo[t], (int)floorf((gx1 - 8.5f - hw) * 0.0625f) - 1);
    int x1 = min(c_xhi[t], (int)ceilf ((gx2 - 6.5f + hw) * 0.0625f) + 1);
    int y0 = max(c_ylo[t], (int)floorf((gy1 - 8.5f - hh) * 0.0625f) - 1);
    int y1 = min(c_yhi[t], (int)ceilf ((gy2 - 6.5f + hh) * 0.0625f) + 1);
    if (x1 < x0 || y1 < y0) continue;
    int x = min(x0 + lane, x1);                    // clamp: dup anchors harmless for max
    float cx = (float)(16 * x) + 7.5f;
    float ax1 = cx - hw, ax2 = cx + hw;
    float aarv = ((ax2 - ax1) + 1.0f) * ((hh + hh) + 1.0f);
    float iw = (fminf(ax2, gx2) - fmaxf(ax1, gx1)) + 1.0f; iw = fmaxf(iw, 0.0f);
    for (int y = y0 + wv; y <= y1; y += 4) {
      float cy = (float)(16 * y) + 7.5f;
      float ay1 = cy - hh, ay2 = cy + hh;
      float ih = (fminf(ay2, gy2) - fmaxf(ay1, gy1)) + 1.0f; ih = fmaxf(ih, 0.0f);
      float inter = iw * ih;
      best = fmaxf(best, inter / ((aarv + gar) - inter));
    }
  }
  for (int off = 32; off > 0; off >>= 1)
    best = fmaxf(best, __shfl_down(best, off));
  __shared__ float red[4];
  if (lane == 0) red[wv] = best;
  __syncthreads();
  if (threadIdx.x == 0)
    gt_max[b * GG + g] = fmaxf(fmaxf(red[0], red[1]), fmaxf(red[2], red[3]));
}

// ---- K2: labels/argmax/candidates — a-major, wave-coherent skip ---------
__global__ void __launch_bounds__(256, 4) k_labels(
    const float* __restrict__ gt, const float4* __restrict__ abox,
    const float* __restrict__ aar, const int* __restrict__ iref,
    const float* __restrict__ gt_max,
    const unsigned* __restrict__ keyf, const unsigned* __restrict__ keyb,
    signed char* __restrict__ lab, unsigned char* __restrict__ am,
    int* __restrict__ fg_cnt, unsigned long long* __restrict__ fg_key, int* __restrict__ fg_j,
    int* __restrict__ bg_cnt, unsigned long long* __restrict__ bg_key, int* __restrict__ bg_j) {
  __shared__ float4 sbox[GG];
  __shared__ float2 sga[GG];      // (area_g, gt_max' = m>0 ? m : -1)
  int b = blockIdx.y;
  if (threadIdx.x < GG) {
    float4 gbx = ((const float4*)(gt + b * GG * 4))[threadIdx.x];
    sbox[threadIdx.x] = gbx;
    float gar = ((gbx.z - gbx.x) + 1.0f) * ((gbx.w - gbx.y) + 1.0f);
    float m = gt_max[b * GG + threadIdx.x];
    sga[threadIdx.x] = make_float2(gar, (m > 0.0f) ? m : -1.0f);
  }
  __syncthreads();
  int j = blockIdx.x * 256 + threadIdx.x;
  bool act = j < NANC;
  int jj = act ? j : (NANC - 1);
  float4 A = abox[jj];
  float av = aar[jj];
  float best = 0.0f; int argg = 0; bool hit = false;
  for (int g = 0; g < GG; ++g) {
    float4 gbx = sbox[g];
    float2 ga = sga[g];
    float iw = (fminf(A.z, gbx.z) - fmaxf(A.x, gbx.x)) + 1.0f; iw = fmaxf(iw, 0.0f);
    float ih = (fminf(A.w, gbx.w) - fmaxf(A.y, gbx.y)) + 1.0f; ih = fmaxf(ih, 0.0f);
    float inter = iw * ih;
    if (inter > 0.0f) {          // ov==0: can't beat best>=0, can't equal ga.y(!=0)
      float ov = inter / ((av + ga.x) - inter);
      if (ov > best) { best = ov; argg = g; }      // first-max wins
      hit = hit || (ov == ga.y);                   // ga.y=-1 if gt_max<=0
    }
  }
  if (!act) return;
  int ir = iref[jj];
  int label = (hit || best >= 0.7f) ? 1 : ((best < 0.3f) ? 0 : -1);
  lab[b * NCAP + j] = (signed char)label;
  am[b * NCAP + j]  = (unsigned char)argg;
  if (label == 1) {
    float p = pri_uniform(keyf[2*b], keyf[2*b+1], ir);
    int cc = atomicAdd(&fg_cnt[b], 1);
    if (cc < MAXC) {
      fg_key[b * MAXC + cc] = ((unsigned long long)__float_as_uint(p) << 32) | (unsigned)ir;
      fg_j[b * MAXC + cc] = j;
    }
  } else if (label == 0) {
    float p = pri_uniform(keyb[2*b], keyb[2*b+1], ir);
    if (p < BG_T) {
      int cc = atomicAdd(&bg_cnt[b], 1);
      if (cc < MAXC) {
        bg_key[b * MAXC + cc] = ((unsigned long long)__float_as_uint(p) << 32) | (unsigned)ir;
        bg_j[b * MAXC + cc] = j;
      }
    }
  }
}

// ---- K3: merged fg/bg subsample via LDS rank-select ---------------------
// Key = (pri bits, iref): pri>=0 so float bits order as u32; iref tie-break
// reproduces stable argsort. Payload = j (a-major index into lab).
__global__ void __launch_bounds__(1024) k_select(
    const int* __restrict__ fg_cnt, const unsigned long long* __restrict__ fg_key,
    const int* __restrict__ fg_j,
    const int* __restrict__ bg_cnt, const unsigned long long* __restrict__ bg_key,
    const int* __restrict__ bg_j,
    signed char* __restrict__ lab) {
  __shared__ unsigned long long sk[MAXC];
  __shared__ int sj[MAXC];
  int b = blockIdx.x & (BB - 1);
  if (blockIdx.x < BB) {        // fg role: demote rank >= NUMFG
    int F = min(fg_cnt[b], MAXC);
    if (F <= NUMFG) return;
    for (int c = threadIdx.x; c < F; c += blockDim.x) {
      sk[c] = fg_key[b * MAXC + c]; sj[c] = fg_j[b * MAXC + c];
    }
    __syncthreads();
    for (int c = threadIdx.x; c < F; c += blockDim.x) {
      unsigned long long me = sk[c];
      int rank = 0;
      for (int jx = 0; jx < F; ++jx) rank += (sk[jx] < me) ? 1 : 0;
      if (rank >= NUMFG) lab[b * NCAP + sj[c]] = -1;
    }
  } else {                       // bg role: mark rank < nk as kept (2)
    int nk = RPNB - min(fg_cnt[b], NUMFG);
    int C = min(bg_cnt[b], MAXC);
    for (int c = threadIdx.x; c < C; c += blockDim.x) {
      sk[c] = bg_key[b * MAXC + c]; sj[c] = bg_j[b * MAXC + c];
    }
    __syncthreads();
    for (int c = threadIdx.x; c < C; c += blockDim.x) {
      unsigned long long me = sk[c];
      int rank = 0;
      for (int jx = 0; jx < C; ++jx) rank += (sk[jx] < me) ? 1 : 0;
      if (rank < nk) lab[b * NCAP + sj[c]] = 2;
    }
  }
}

// ---- K4: fill+scatter, output-ordered, analytic j (no inverse table) ----
__global__ void k_out(const float* __restrict__ gt,
                      const signed char* __restrict__ lab, const unsigned char* __restrict__ am,
                      float* __restrict__ out) {
  int b = blockIdx.y;
  int t = blockIdx.x * 256 + threadIdx.x;   // t = a*4096 + y*64 + x  (output order)
  int a = t >> 12, pos = t & 4095;          // a is block-uniform (4096/256=16)
  int y = pos >> 6, x = pos & 63;
  int j = -1;
  if (x >= c_xlo[a] && x <= c_xhi[a] && y >= c_ylo[a] && y <= c_yhi[a])
    j = c_base[a] + (y - c_ylo[a]) * c_nx[a] + (x - c_xlo[a]);
  float lv = -1.0f, t0 = 0.f, t1 = 0.f, t2 = 0.f, t3 = 0.f;
  if (j >= 0) {
    signed char v = lab[b * NCAP + j];
    lv = (v == 1) ? 1.0f : ((v == 2) ? 0.0f : -1.0f);
    if (v == 1) {
      float ax1, ay1, ax2, ay2;
      box_from_ayx(a, x, y, ax1, ay1, ax2, ay2);
      int g = am[b * NCAP + j];
      const float* gr = gt + (b * GG + g) * 4;
      float gx1 = gr[0], gy1 = gr[1], gx2 = gr[2], gy2 = gr[3];
      float aw = (ax2 - ax1) + 1.0f, ah = (ay2 - ay1) + 1.0f;
      float acx = ax1 + 0.5f * (aw - 1.0f), acy = ay1 + 0.5f * (ah - 1.0f);
      float gw = (gx2 - gx1) + 1.0f, gh = (gy2 - gy1) + 1.0f;
      float gcx = gx1 + 0.5f * (gw - 1.0f), gcy = gy1 + 0.5f * (gh - 1.0f);
      t0 = (gcx - acx) / aw;
      t1 = (gcy - acy) / ah;
      t2 = logf(gw / aw);
      t3 = logf(gh / ah);
    }
  }
  out[b * KAT + t] = lv;
  float* rb = out + LAB_SZ + b * (4 * KAT) + (a * 4) * 4096 + pos;
  rb[0] = t0; rb[4096] = t1; rb[2 * 4096] = t2; rb[3 * 4096] = t3;
}

extern "C" void kernel_launch(void* const* d_in, const int* in_sizes, int n_in,
                              void* d_out, int out_size, void* d_ws, size_t ws_size,
                              hipStream_t stream) {
  const float* gt = (const float*)d_in[0];
  float* out = (float*)d_out;

  char* w = (char*)d_ws;
  float4* abox     = (float4*)w;         w += NCAP*sizeof(float4);    // 327680 (16B aligned)
  unsigned long long* fg_key = (unsigned long long*)w; w += BB*MAXC*8;
  unsigned long long* bg_key = (unsigned long long*)w; w += BB*MAXC*8;
  float* aar       = (float*)w;          w += NCAP*sizeof(float);
  int* iref        = (int*)w;            w += NCAP*sizeof(int);
  int* fg_cnt      = (int*)w;            w += 256;
  int* bg_cnt      = (int*)w;            w += 256;
  unsigned* keyf   = (unsigned*)w;       w += 256;
  unsigned* keyb   = (unsigned*)w;       w += 256;
  float* gt_max    = (float*)w;          w += ((BB*GG*4 + 255)/256)*256;
  int* fg_j        = (int*)w;            w += BB*MAXC*sizeof(int);
  int* bg_j        = (int*)w;            w += BB*MAXC*sizeof(int);
  signed char* lab = (signed char*)w;    w += BB*NCAP;
  unsigned char* am= (unsigned char*)w;  w += BB*NCAP;
  // total ~4.9 MB of d_ws

  k_pg<<<NGTB + NPREPB, 256, 0, stream>>>(gt, abox, aar, iref, keyf, keyb,
                                          fg_cnt, bg_cnt, gt_max);
  k_labels<<<dim3((NANC + 255)/256, BB), 256, 0, stream>>>(gt, abox, aar, iref, gt_max,
                                                           keyf, keyb, lab, am,
                                                           fg_cnt, fg_key, fg_j,
                                                           bg_cnt, bg_key, bg_j);
  k_select<<<2*BB, 1024, 0, stream>>>(fg_cnt, fg_key, fg_j, bg_cnt, bg_key, bg_j, lab);
  k_out<<<dim3(KAT/256, BB), 256, 0, stream>>>(gt, lab, am, out);
}